// Round 8
// baseline (334.978 us; speedup 1.0000x reference)
//
#include <hip/hip_runtime.h>
#include <hip/hip_bf16.h>

// SynthesisConv: style affine -> demod -> conv_transpose(up=2,k=3) -> FIR 4x4
// -> noise + bias + lrelu*sqrt(2) + clamp(+-256).  Inputs f32, output f32.
//
//   style folds into x (B-operand column scale), dcoef folds into epilogue.
//   Z[(o,ky,kx),(b,i,j)] = sum_c w[o,c,ky,kx] * x'[b,c,i,j]   (one shared GEMM)
// R7: k_gemm LDS chunk-swizzle kills the 8-way ds_read_b128 bank conflict.
// R8: 256x256, 4-buffer ring, counted vmcnt, setprio (null).
// R9: XCD swizzle (REGRESSED); k_style coalesced rewrite kept.
// R10: barriers 5->1 per K-tile + LDS-staged coalesced C-write (WIN).
// R11: k_scatter 512 thr -> 24 waves/CU (WIN).
// R12: m201-style 4-phase fine interleave (null; schedule family exhausted).
// R13: k_gemm 128x256, 2 blocks/CU (WIN 102.8->92.9; occupancy is the axis).
// R14: k_scatter phase-3 + k_xt vectorize (WIN 338->321; gemm flat = clean).
// R15: k_gemm -> 128x128, 4 waves, 32 KB LDS (2-buf ring + chunked 2-pass
//      C-staging), launch_bounds(256,4): VGPR+AGPR<=128 -> 4 blocks/CU =
//      16 waves in 4 INDEPENDENT barrier groups (was 2). Drain-0 boundary
//      (2-buf) accepted: staggered blocks hide each other's drains (R13
//      mechanism). Same per-wave code path as R13.

typedef unsigned short u16;
typedef unsigned int u32;
typedef u16 u16x2 __attribute__((ext_vector_type(2)));
typedef u16 u16x8 __attribute__((ext_vector_type(8)));
typedef __bf16 bf16x8 __attribute__((ext_vector_type(8)));
typedef float f32x4 __attribute__((ext_vector_type(4)));

#define NB 16

__device__ __forceinline__ float bf2f(u16 v) {
  unsigned int u = ((unsigned int)v) << 16;
  float f;
  __builtin_memcpy(&f, &u, 4);
  return f;
}
__device__ __forceinline__ u16 f2bf(float f) {
  __hip_bfloat16 h = __float2bfloat16(f);  // RNE
  u16 r;
  __builtin_memcpy(&r, &h, 2);
  return r;
}
__device__ __forceinline__ void async16(u16* lds, const u16* g) {
  __builtin_amdgcn_global_load_lds(
      (const __attribute__((address_space(1))) u32*)g,
      (__attribute__((address_space(3))) u32*)lds, 16, 0, 0);
}

// ---- style[b,c] = sum_k wl[b,k]*aw[c,k]/sqrt(512) + ab[c] ---------------------
__global__ __launch_bounds__(256) void k_style(const float* __restrict__ wl,
                                               const float* __restrict__ aw,
                                               const float* __restrict__ ab,
                                               float* __restrict__ style) {
  __shared__ float lw[512];
  const int b = blockIdx.y;
  const int c0 = blockIdx.x << 6;
  const int t = threadIdx.x;
  for (int k = t; k < 512; k += 256) lw[k] = wl[b * 512 + k];
  __syncthreads();
  const int w = t >> 6, l = t & 63;
  const float4 lv0 = *(const float4*)(lw + (l << 2));
  const float4 lv1 = *(const float4*)(lw + 256 + (l << 2));
  for (int r = w; r < 64; r += 4) {
    const int c = c0 + r;
    const float* row = aw + (size_t)c * 512 + (l << 2);
    const float4 a0 = *(const float4*)(row);
    const float4 a1 = *(const float4*)(row + 256);
    float acc = lv0.x * a0.x + lv0.y * a0.y + lv0.z * a0.z + lv0.w * a0.w +
                lv1.x * a1.x + lv1.y * a1.y + lv1.z * a1.z + lv1.w * a1.w;
#pragma unroll
    for (int off = 32; off; off >>= 1) acc += __shfl_down(acc, off, 64);
    if (l == 0) style[b * 512 + c] = acc * 0.04419417382415922f + ab[c];
  }
}

// ---- merged: W2 pack (bf16, [o*9+kp][c]) + dcoef[b,o] ------------------------
__global__ __launch_bounds__(256) void k_wprep(const float* __restrict__ cw,
                                               const float* __restrict__ style,
                                               float* __restrict__ dcoef,
                                               u16* __restrict__ W2) {
  __shared__ u16 lw[4608];
  __shared__ float wsq[512];
  const int o = blockIdx.x, t = threadIdx.x;
  const float* src = cw + (size_t)o * 4608;
  for (int v = t; v < 4608; v += 256) {
    unsigned c = (unsigned)v / 9u;
    unsigned kp = (unsigned)v % 9u;
    lw[kp * 512 + c] = f2bf(src[v]);
  }
  for (int c = t; c < 512; c += 256) {
    const float* p = src + (size_t)c * 9;
    float s = 0.f;
#pragma unroll
    for (int k = 0; k < 9; ++k) {
      float v = p[k];
      s += v * v;
    }
    wsq[c] = s;
  }
  __syncthreads();
  u16* dst = W2 + (size_t)o * 4608;
  for (int v = t; v < 576; v += 256)
    *(u16x8*)(dst + v * 8) = *(const u16x8*)(lw + v * 8);
  const int w = t >> 6, l = t & 63;
  for (int b = w; b < NB; b += 4) {
    float part = 0.f;
#pragma unroll
    for (int c = l; c < 512; c += 64) {
      float st = style[b * 512 + c];
      part += st * st * wsq[c];
    }
#pragma unroll
    for (int off = 32; off; off >>= 1) part += __shfl_down(part, off, 64);
    if (l == 0) dcoef[b * 512 + o] = 1.0f / sqrtf(part + 1e-8f);
  }
}

// ---- xT[b,s,c] = bf16(x[b,c,s] * style[b,c])  (LDS 64x64 transpose) ----------
__global__ __launch_bounds__(256) void k_xt(const float* __restrict__ x,
                                            const float* __restrict__ style,
                                            u16* __restrict__ xT) {
  __shared__ u16 tile[64 * 66];
  const int b = blockIdx.z, c0 = blockIdx.y << 6, s0 = blockIdx.x << 6;
  const int t = threadIdx.x;
#pragma unroll
  for (int i = 0; i < 4; ++i) {
    int e = i * 256 + t;
    int cc = e >> 4, f4 = e & 15;   // 64 rows x 16 float4
    int c = c0 + cc;
    float4 v = *(const float4*)(x + (size_t)(b * 512 + c) * 1024 + s0 + f4 * 4);
    float sv = style[b * 512 + c];
    int base = cc * 66 + f4 * 4;    // even -> 4B aligned for u16x2
    u16x2 p0, p1;
    p0[0] = f2bf(v.x * sv);
    p0[1] = f2bf(v.y * sv);
    p1[0] = f2bf(v.z * sv);
    p1[1] = f2bf(v.w * sv);
    *(u16x2*)(tile + base) = p0;
    *(u16x2*)(tile + base + 2) = p1;
  }
  __syncthreads();
#pragma unroll
  for (int e = 0; e < 2; ++e) {
    int idx = e * 256 + t;          // 512 = 64 rows x 8 col-groups
    int sc = idx >> 3;
    int cg = (idx & 7) << 3;
    u16x8 v;
#pragma unroll
    for (int g = 0; g < 8; ++g) v[g] = tile[(cg + g) * 66 + sc];
    *(u16x8*)(xT + (size_t)(b * 1024 + s0 + sc) * 512 + c0 + cg) = v;
  }
}

// ---- GEMM: Z[4608 x 16384] = W2[4608 x 512] * xT[16384 x 512]^T --------------
// R15: 128x128 tile, BK=32, 4 waves (2M x 2N, wave tile 64x64, acc[4][4]).
// 2-buffer ring (A 8KB + B 8KB per buf = 32 KiB), drain-0 boundary,
// 1 barrier/tile, setprio. 4 blocks/CU. R7 chunk swizzle.
// C epilogue: two 64-row passes through LDS [64][136] (union with ring).
__global__ __launch_bounds__(256, 4) void k_gemm(const u16* __restrict__ W2,
                                                 const u16* __restrict__ xT,
                                                 u16* __restrict__ Z) {
  __shared__ union SM {
    struct { u16 A[2][4096]; u16 B[2][4096]; } g;  // 32 KiB ring
    u16 C[64 * 136];                               // 17 KiB epilogue chunk
  } sm;
  const int t = threadIdx.x;
  const int m0 = blockIdx.y << 7;   // 36 m-blocks
  const int n0 = blockIdx.x << 7;   // 128 n-blocks
  const int l = t & 63;
  const int w = t >> 6;        // wave 0..3
  const int wm = w >> 1;       // 0..1  (M half: 64 rows)
  const int wn = w & 1;        // 0..1  (N half: 64 cols)
  const int lrow = l & 15;
  const int lk = l >> 4;       // k-chunk 0..3

  // staging: 256 thr cover 64 rows x 4 slots per call; 2 calls per 128-row
  // slab. R7 swizzle: row r slot s holds chunk (s+(r>>1))&3; +64 rows keeps
  // the invariant (64>>1 = 32 == 0 mod 4).
  const int sr = t >> 2;
  const int sch = ((t & 3) + (sr >> 1)) & 3;
  const u16* gA = W2 + (size_t)(m0 + sr) * 512 + (sch << 3);
  const u16* gB = xT + (size_t)(n0 + sr) * 512 + (sch << 3);
  const int stg = t << 3;      // u16 offset within 4 KB half-slab

  const int sk8 = ((lk - (lrow >> 1)) & 3) << 3;
  const int arow = (wm << 6) + lrow;
  const int brow = (wn << 6) + lrow;

  f32x4 acc[4][4] = {};

  // one K-tile stage = 4 async16: A rows 0-63, A 64-127, B 0-63, B 64-127
#define STG(buf_, kt_)                                              \
  async16(&sm.g.A[buf_][stg], gA + (kt_) * 32);                     \
  async16(&sm.g.A[buf_][2048 + stg], gA + (kt_) * 32 + 64 * 512);   \
  async16(&sm.g.B[buf_][stg], gB + (kt_) * 32);                     \
  async16(&sm.g.B[buf_][2048 + stg], gB + (kt_) * 32 + 64 * 512)

  STG(0, 0);
  asm volatile("s_waitcnt vmcnt(0)" ::: "memory");
  asm volatile("s_barrier" ::: "memory");

  for (int kt = 0; kt < 16; ++kt) {
    const int buf = kt & 1;
    const u16* Ab = sm.g.A[buf];
    const u16* Bb = sm.g.B[buf];
    bf16x8 av[4], bv[4];
#pragma unroll
    for (int i = 0; i < 4; ++i)
      av[i] = *(const bf16x8*)(Ab + (arow + i * 16) * 32 + sk8);
#pragma unroll
    for (int j = 0; j < 4; ++j)
      bv[j] = *(const bf16x8*)(Bb + (brow + j * 16) * 32 + sk8);
    if (kt < 15) { STG(buf ^ 1, kt + 1); }
    asm volatile("s_waitcnt lgkmcnt(0)" ::: "memory");
    __builtin_amdgcn_sched_barrier(0);
    __builtin_amdgcn_s_setprio(1);
#pragma unroll
    for (int i = 0; i < 4; ++i)
#pragma unroll
      for (int j = 0; j < 4; ++j)
        acc[i][j] = __builtin_amdgcn_mfma_f32_16x16x32_bf16(av[i], bv[j], acc[i][j], 0, 0, 0);
    __builtin_amdgcn_s_setprio(0);
    // boundary: next tile's 4 loads must land (2-buf -> drain); blocks are
    // staggered 4/CU so other blocks' MFMA covers this stall.
    if (kt < 15) {
      asm volatile("s_waitcnt vmcnt(0)" ::: "memory");
    }
    asm volatile("s_barrier" ::: "memory");
  }
#undef STG

  // epilogue: two 64-row passes; pass p = rows of waves with wm==p.
  const int crow0 = (lk << 2);
  const int ccol0 = (wn << 6) + lrow;
  u16* zb = Z + (size_t)m0 * 16384 + n0;
#pragma unroll
  for (int p = 0; p < 2; ++p) {
    __syncthreads();  // ring (or previous chunk) dead
    if (wm == p) {
#pragma unroll
      for (int i = 0; i < 4; ++i)
#pragma unroll
        for (int j = 0; j < 4; ++j)
#pragma unroll
          for (int r = 0; r < 4; ++r)
            sm.C[(crow0 + i * 16 + r) * 136 + ccol0 + j * 16] = f2bf(acc[i][j][r]);
    }
    __syncthreads();
    // 64 rows x 16 chunks of 16B = 1024 chunks; 4 per thread.
#pragma unroll
    for (int k = 0; k < 4; ++k) {
      int c = (k << 8) | t;
      int row = c >> 4;
      int c8 = (c & 15) << 3;
      *(u16x8*)(zb + (size_t)(p * 64 + row) * 16384 + c8) =
          *(const u16x8*)(sm.C + row * 136 + c8);
    }
  }
}

// ---- scatter: polyphase separable FIR + epilogue -----------------------------
__global__ __launch_bounds__(512) void k_scatter(
    const u16* __restrict__ Z, const float* __restrict__ dcoef,
    const float* __restrict__ noise, const float* __restrict__ nstr,
    const float* __restrict__ bias, float* __restrict__ out) {
  __shared__ u16 Zl[9 * 1024];
  __shared__ float Hl[3 * 2048];
  const int o = blockIdx.x;
  const int b = blockIdx.y;
  const int t = threadIdx.x;
  const u16* Zp = Z + (size_t)o * 9 * 16384 + (size_t)b * 1024;
  for (int v = t; v < 1152; v += 512) {
    int kp = v >> 7, off = (v & 127) << 3;
    *(u16x8*)(Zl + kp * 1024 + off) = *(const u16x8*)(Zp + (size_t)kp * 16384 + off);
  }
  __syncthreads();
#pragma unroll
  for (int e = 0; e < 6; ++e) {
    int idx = e * 512 + t;
    int ky = idx >> 10;
    int i = (idx >> 5) & 31;
    int j = idx & 31;
    const u16* P0 = Zl + (ky * 3 + 0) * 1024 + i * 32;
    const u16* P1 = P0 + 1024;
    const u16* P2 = P0 + 2048;
    float Ej = bf2f(P0[j]) + (j >= 1 ? bf2f(P2[j - 1]) : 0.f);
    float Ej1 = (j < 31 ? bf2f(P0[j + 1]) : 0.f) + bf2f(P2[j]);
    float Ojm = j >= 1 ? bf2f(P1[j - 1]) : 0.f;
    float Oj = bf2f(P1[j]);
    float Ojp = j < 31 ? bf2f(P1[j + 1]) : 0.f;
    float* hp = Hl + ky * 2048 + i * 64 + j;
    hp[0] = Ojm + 3.f * Ej + 3.f * Oj + Ej1;
    hp[32] = Ej + 3.f * Oj + 3.f * Ej1 + Ojp;
  }
  __syncthreads();
  const float dc = dcoef[b * 512 + o] * 0.0625f;
  const float ns = nstr[0];
  const float bo = bias[o];
  const int q = t & 15;           // j-quad: cols 4q..4q+3
  const int i = t >> 4;           // 0..31 -> out rows 2i, 2i+1
  const int cb = 2 * q;           // column base within H halves
#define LD2(ky_, r_) *(const float2*)(Hl + (ky_) * 2048 + (r_) * 64 + cb)
#define LD2H(ky_, r_) *(const float2*)(Hl + (ky_) * 2048 + (r_) * 64 + 32 + cb)
  const float2 z2 = {0.f, 0.f};
  float2 A0c = LD2(0, i), B0c = LD2H(0, i);
  float2 A1c = LD2(1, i), B1c = LD2H(1, i);
  float2 A2c = LD2(2, i), B2c = LD2H(2, i);
  float2 A0n = (i < 31) ? LD2(0, i + 1) : z2;
  float2 B0n = (i < 31) ? LD2H(0, i + 1) : z2;
  float2 A1n = (i < 31) ? LD2(1, i + 1) : z2;
  float2 B1n = (i < 31) ? LD2H(1, i + 1) : z2;
  float2 A1p = (i > 0) ? LD2(1, i - 1) : z2;
  float2 B1p = (i > 0) ? LD2H(1, i - 1) : z2;
  float2 A2p = (i > 0) ? LD2(2, i - 1) : z2;
  float2 B2p = (i > 0) ? LD2H(2, i - 1) : z2;
#undef LD2
#undef LD2H
  const int m = 2 * i;
  const float* nzb = noise + ((size_t)b << 12) + (size_t)m * 64 + 4 * q;
  const float4 nz0 = *(const float4*)(nzb);
  const float4 nz1 = *(const float4*)(nzb + 64);
  float ev[4], od[4];
#define COLS(c_, f_)                                                     \
  ev[c_] = f_(A1p, B1p) + 3.f * (f_(A0c, B0c) + f_(A2p, B2p)) +          \
           3.f * f_(A1c, B1c) + (f_(A0n, B0n) + f_(A2c, B2c));           \
  od[c_] = (f_(A0c, B0c) + f_(A2p, B2p)) + 3.f * f_(A1c, B1c) +          \
           3.f * (f_(A0n, B0n) + f_(A2c, B2c)) + f_(A1n, B1n)
#define FAX(a_, b_) (a_.x)
#define FBX(a_, b_) (b_.x)
#define FAY(a_, b_) (a_.y)
#define FBY(a_, b_) (b_.y)
  COLS(0, FAX);
  COLS(1, FBX);
  COLS(2, FAY);
  COLS(3, FBY);
#undef COLS
#undef FAX
#undef FBX
#undef FAY
#undef FBY
  float4 r0, r1;
  {
    const float nzs0[4] = {nz0.x, nz0.y, nz0.z, nz0.w};
    const float nzs1[4] = {nz1.x, nz1.y, nz1.z, nz1.w};
    float o0[4], o1[4];
#pragma unroll
    for (int c = 0; c < 4; ++c) {
      float v0 = ev[c] * dc + nzs0[c] * ns + bo;
      v0 = (v0 > 0.f ? v0 : 0.2f * v0) * 1.4142135623730951f;
      o0[c] = fminf(fmaxf(v0, -256.f), 256.f);
      float v1 = od[c] * dc + nzs1[c] * ns + bo;
      v1 = (v1 > 0.f ? v1 : 0.2f * v1) * 1.4142135623730951f;
      o1[c] = fminf(fmaxf(v1, -256.f), 256.f);
    }
    r0 = {o0[0], o0[1], o0[2], o0[3]};
    r1 = {o1[0], o1[1], o1[2], o1[3]};
  }
  float* ob = out + (((size_t)(b * 512 + o)) << 12) + (size_t)m * 64 + 4 * q;
  *(float4*)(ob) = r0;
  *(float4*)(ob + 64) = r1;
}

extern "C" void kernel_launch(void* const* d_in, const int* in_sizes, int n_in,
                              void* d_out, int out_size, void* d_ws, size_t ws_size,
                              hipStream_t stream) {
  const float* x = (const float*)d_in[0];
  const float* wl = (const float*)d_in[1];
  const float* aw = (const float*)d_in[2];
  const float* ab = (const float*)d_in[3];
  const float* cw = (const float*)d_in[4];
  const float* noise = (const float*)d_in[5];
  const float* nstr = (const float*)d_in[6];
  const float* bias = (const float*)d_in[7];
  float* out = (float*)d_out;

  float* style = (float*)d_ws;
  float* dcoef = style + 8192;
  u16* W2 = (u16*)(dcoef + 8192);
  u16* xT = W2 + 4608 * 512;
  u16* Z = xT + (size_t)16384 * 512;

  k_style<<<dim3(8, 16), 256, 0, stream>>>(wl, aw, ab, style);
  k_wprep<<<dim3(512), 256, 0, stream>>>(cw, style, dcoef, W2);
  k_xt<<<dim3(16, 8, 16), 256, 0, stream>>>(x, style, xT);
  k_gemm<<<dim3(128, 36), 256, 0, stream>>>(W2, xT, Z);
  k_scatter<<<dim3(512, 16), 512, 0, stream>>>(Z, dcoef, noise, nstr, bias, out);
}

// Round 10
// 323.736 us; speedup vs baseline: 1.0347x; 1.0347x over previous
//
#include <hip/hip_runtime.h>
#include <hip/hip_bf16.h>

// SynthesisConv: style affine -> demod -> conv_transpose(up=2,k=3) -> FIR 4x4
// -> noise + bias + lrelu*sqrt(2) + clamp(+-256).  Inputs f32, output f32.
//
//   style folds into x (B-operand column scale), dcoef folds into epilogue.
//   Z[(o,ky,kx),(b,i,j)] = sum_c w[o,c,ky,kx] * x'[b,c,i,j]   (one shared GEMM)
// R7: k_gemm LDS chunk-swizzle kills the 8-way ds_read_b128 bank conflict.
// R8: 256x256, 4-buffer ring, counted vmcnt, setprio (null).
// R9: XCD swizzle (REGRESSED); k_style coalesced rewrite kept.
// R10: barriers 5->1 per K-tile + LDS-staged coalesced C-write (WIN).
// R11: k_scatter 512 thr -> 24 waves/CU (WIN).
// R12: m201-style 4-phase fine interleave (null; schedule family exhausted).
// R13: k_gemm 128x256, 2 blocks/CU (WIN 102.8->92.9).
// R14: k_scatter phase-3 + k_xt vectorize (WIN 338->321; gemm flat).
// R15: k_gemm 128x128 4-block attempt (REGRESSED; axis closed).
// R16: gemm restored to R13 verbatim + k_scatter Z staging via global_load_lds.
//      Bench infra failed ("container failed twice") -> R17 resubmits the
//      identical source (staging audited: wave-uniform base + lane-linear
//      dest, exact bounds, wave-granular exec; semantically sound).

typedef unsigned short u16;
typedef unsigned int u32;
typedef u16 u16x2 __attribute__((ext_vector_type(2)));
typedef u16 u16x8 __attribute__((ext_vector_type(8)));
typedef __bf16 bf16x8 __attribute__((ext_vector_type(8)));
typedef float f32x4 __attribute__((ext_vector_type(4)));

#define NB 16

__device__ __forceinline__ float bf2f(u16 v) {
  unsigned int u = ((unsigned int)v) << 16;
  float f;
  __builtin_memcpy(&f, &u, 4);
  return f;
}
__device__ __forceinline__ u16 f2bf(float f) {
  __hip_bfloat16 h = __float2bfloat16(f);  // RNE
  u16 r;
  __builtin_memcpy(&r, &h, 2);
  return r;
}
__device__ __forceinline__ void async16(u16* lds, const u16* g) {
  __builtin_amdgcn_global_load_lds(
      (const __attribute__((address_space(1))) u32*)g,
      (__attribute__((address_space(3))) u32*)lds, 16, 0, 0);
}

// ---- style[b,c] = sum_k wl[b,k]*aw[c,k]/sqrt(512) + ab[c] ---------------------
__global__ __launch_bounds__(256) void k_style(const float* __restrict__ wl,
                                               const float* __restrict__ aw,
                                               const float* __restrict__ ab,
                                               float* __restrict__ style) {
  __shared__ float lw[512];
  const int b = blockIdx.y;
  const int c0 = blockIdx.x << 6;
  const int t = threadIdx.x;
  for (int k = t; k < 512; k += 256) lw[k] = wl[b * 512 + k];
  __syncthreads();
  const int w = t >> 6, l = t & 63;
  const float4 lv0 = *(const float4*)(lw + (l << 2));
  const float4 lv1 = *(const float4*)(lw + 256 + (l << 2));
  for (int r = w; r < 64; r += 4) {
    const int c = c0 + r;
    const float* row = aw + (size_t)c * 512 + (l << 2);
    const float4 a0 = *(const float4*)(row);
    const float4 a1 = *(const float4*)(row + 256);
    float acc = lv0.x * a0.x + lv0.y * a0.y + lv0.z * a0.z + lv0.w * a0.w +
                lv1.x * a1.x + lv1.y * a1.y + lv1.z * a1.z + lv1.w * a1.w;
#pragma unroll
    for (int off = 32; off; off >>= 1) acc += __shfl_down(acc, off, 64);
    if (l == 0) style[b * 512 + c] = acc * 0.04419417382415922f + ab[c];
  }
}

// ---- merged: W2 pack (bf16, [o*9+kp][c]) + dcoef[b,o] ------------------------
__global__ __launch_bounds__(256) void k_wprep(const float* __restrict__ cw,
                                               const float* __restrict__ style,
                                               float* __restrict__ dcoef,
                                               u16* __restrict__ W2) {
  __shared__ u16 lw[4608];
  __shared__ float wsq[512];
  const int o = blockIdx.x, t = threadIdx.x;
  const float* src = cw + (size_t)o * 4608;
  for (int v = t; v < 4608; v += 256) {
    unsigned c = (unsigned)v / 9u;
    unsigned kp = (unsigned)v % 9u;
    lw[kp * 512 + c] = f2bf(src[v]);
  }
  for (int c = t; c < 512; c += 256) {
    const float* p = src + (size_t)c * 9;
    float s = 0.f;
#pragma unroll
    for (int k = 0; k < 9; ++k) {
      float v = p[k];
      s += v * v;
    }
    wsq[c] = s;
  }
  __syncthreads();
  u16* dst = W2 + (size_t)o * 4608;
  for (int v = t; v < 576; v += 256)
    *(u16x8*)(dst + v * 8) = *(const u16x8*)(lw + v * 8);
  const int w = t >> 6, l = t & 63;
  for (int b = w; b < NB; b += 4) {
    float part = 0.f;
#pragma unroll
    for (int c = l; c < 512; c += 64) {
      float st = style[b * 512 + c];
      part += st * st * wsq[c];
    }
#pragma unroll
    for (int off = 32; off; off >>= 1) part += __shfl_down(part, off, 64);
    if (l == 0) dcoef[b * 512 + o] = 1.0f / sqrtf(part + 1e-8f);
  }
}

// ---- xT[b,s,c] = bf16(x[b,c,s] * style[b,c])  (LDS 64x64 transpose) ----------
__global__ __launch_bounds__(256) void k_xt(const float* __restrict__ x,
                                            const float* __restrict__ style,
                                            u16* __restrict__ xT) {
  __shared__ u16 tile[64 * 66];
  const int b = blockIdx.z, c0 = blockIdx.y << 6, s0 = blockIdx.x << 6;
  const int t = threadIdx.x;
#pragma unroll
  for (int i = 0; i < 4; ++i) {
    int e = i * 256 + t;
    int cc = e >> 4, f4 = e & 15;   // 64 rows x 16 float4
    int c = c0 + cc;
    float4 v = *(const float4*)(x + (size_t)(b * 512 + c) * 1024 + s0 + f4 * 4);
    float sv = style[b * 512 + c];
    int base = cc * 66 + f4 * 4;    // even -> 4B aligned for u16x2
    u16x2 p0, p1;
    p0[0] = f2bf(v.x * sv);
    p0[1] = f2bf(v.y * sv);
    p1[0] = f2bf(v.z * sv);
    p1[1] = f2bf(v.w * sv);
    *(u16x2*)(tile + base) = p0;
    *(u16x2*)(tile + base + 2) = p1;
  }
  __syncthreads();
#pragma unroll
  for (int e = 0; e < 2; ++e) {
    int idx = e * 256 + t;          // 512 = 64 rows x 8 col-groups
    int sc = idx >> 3;
    int cg = (idx & 7) << 3;
    u16x8 v;
#pragma unroll
    for (int g = 0; g < 8; ++g) v[g] = tile[(cg + g) * 66 + sc];
    *(u16x8*)(xT + (size_t)(b * 1024 + s0 + sc) * 512 + c0 + cg) = v;
  }
}

// ---- GEMM: Z[4608 x 16384] = W2[4608 x 512] * xT[16384 x 512]^T --------------
// R13 (restored verbatim): 128x256 tile, BK=32, 8 waves (2M x 4N, wave tile
// 64x64, acc[4][4]). 3-buffer ring, 2-tile-deep prefetch, counted vmcnt(3),
// 1 barrier/tile, setprio. 2 blocks/CU. R7 chunk swizzle. C via LDS union.
__global__ __launch_bounds__(512, 4) void k_gemm(const u16* __restrict__ W2,
                                                 const u16* __restrict__ xT,
                                                 u16* __restrict__ Z) {
  __shared__ union SM {
    struct { u16 A[3][4096]; u16 B[3][8192]; } g;  // 72 KiB ring
    u16 C[128 * 264];                              // 66 KiB epilogue tile
  } sm;
  const int t = threadIdx.x;
  const int m0 = blockIdx.y << 7;   // 36 m-blocks
  const int n0 = blockIdx.x << 8;   // 64 n-blocks
  const int l = t & 63;
  const int w = t >> 6;        // wave 0..7
  const int wm = w >> 2;       // 0..1  (M half: 64 rows)
  const int wn = w & 3;        // 0..3  (N quarter: 64 cols)
  const int lrow = l & 15;
  const int lk = l >> 4;       // k-chunk 0..3

  const int sr = t >> 2;
  const int sch = ((t & 3) + (sr >> 1)) & 3;
  const u16* gA = W2 + (size_t)(m0 + sr) * 512 + (sch << 3);
  const u16* gB = xT + (size_t)(n0 + sr) * 512 + (sch << 3);
  const int stg = t << 3;      // u16 offset in 8 KB slab

  const int sk8 = ((lk - (lrow >> 1)) & 3) << 3;
  const int arow = (wm << 6) + lrow;
  const int brow = (wn << 6) + lrow;

  f32x4 acc[4][4] = {};

#define STG(buf_, kt_)                                              \
  async16(&sm.g.A[buf_][stg], gA + (kt_) * 32);                     \
  async16(&sm.g.B[buf_][stg], gB + (kt_) * 32);                     \
  async16(&sm.g.B[buf_][4096 + stg], gB + (kt_) * 32 + 128 * 512)

  STG(0, 0);
  STG(1, 1);
  asm volatile("s_waitcnt vmcnt(3)" ::: "memory");
  asm volatile("s_barrier" ::: "memory");

  int buf = 0, nxt = 2;
  for (int kt = 0; kt < 16; ++kt) {
    const u16* Ab = sm.g.A[buf];
    const u16* Bb = sm.g.B[buf];
    bf16x8 av[4], bv[4];
#pragma unroll
    for (int i = 0; i < 4; ++i)
      av[i] = *(const bf16x8*)(Ab + (arow + i * 16) * 32 + sk8);
#pragma unroll
    for (int j = 0; j < 4; ++j)
      bv[j] = *(const bf16x8*)(Bb + (brow + j * 16) * 32 + sk8);
    if (kt < 14) { STG(nxt, kt + 2); }
    asm volatile("s_waitcnt lgkmcnt(0)" ::: "memory");
    __builtin_amdgcn_sched_barrier(0);
    __builtin_amdgcn_s_setprio(1);
#pragma unroll
    for (int i = 0; i < 4; ++i)
#pragma unroll
      for (int j = 0; j < 4; ++j)
        acc[i][j] = __builtin_amdgcn_mfma_f32_16x16x32_bf16(av[i], bv[j], acc[i][j], 0, 0, 0);
    __builtin_amdgcn_s_setprio(0);
    if (kt <= 13) {
      asm volatile("s_waitcnt vmcnt(3)" ::: "memory");
    } else if (kt == 14) {
      asm volatile("s_waitcnt vmcnt(0)" ::: "memory");
    }
    asm volatile("s_barrier" ::: "memory");
    buf = (buf == 2) ? 0 : buf + 1;
    nxt = (nxt == 2) ? 0 : nxt + 1;
  }
#undef STG

  __syncthreads();  // ring dead; reuse LDS as C tile
  const int crow0 = (wm << 6) + (lk << 2);
  const int ccol0 = (wn << 6) + lrow;
#pragma unroll
  for (int i = 0; i < 4; ++i)
#pragma unroll
    for (int j = 0; j < 4; ++j)
#pragma unroll
      for (int r = 0; r < 4; ++r)
        sm.C[(crow0 + i * 16 + r) * 264 + ccol0 + j * 16] = f2bf(acc[i][j][r]);
  __syncthreads();
  u16* zb = Z + (size_t)m0 * 16384 + n0;
#pragma unroll
  for (int k = 0; k < 8; ++k) {
    int c = (k << 9) | t;
    int row = c >> 5;
    int c8 = (c & 31) << 3;
    *(u16x8*)(zb + (size_t)row * 16384 + c8) = *(const u16x8*)(sm.C + row * 264 + c8);
  }
}

// ---- scatter: polyphase separable FIR + epilogue -----------------------------
// R16: Z staging via global_load_lds (no VGPR roundtrip). Chunk v = t + 512k:
// wave spans a 64-aligned range inside each 128-chunk kp-row -> base is
// wave-uniform, dest Zl + v*16B is lane-linear. 3rd pass waves 0-1 only.
__global__ __launch_bounds__(512) void k_scatter(
    const u16* __restrict__ Z, const float* __restrict__ dcoef,
    const float* __restrict__ noise, const float* __restrict__ nstr,
    const float* __restrict__ bias, float* __restrict__ out) {
  __shared__ u16 Zl[9 * 1024];
  __shared__ float Hl[3 * 2048];
  const int o = blockIdx.x;
  const int b = blockIdx.y;
  const int t = threadIdx.x;
  const u16* Zp = Z + (size_t)o * 9 * 16384 + (size_t)b * 1024;
  for (int v = t; v < 1152; v += 512) {
    // chunk v: kp = v>>7, 16B offset (v&127)*16; Zl dest linear at v*16B.
    async16(Zl + (v << 3), Zp + (size_t)(v >> 7) * 16384 + ((v & 127) << 3));
  }
  asm volatile("s_waitcnt vmcnt(0)" ::: "memory");
  __syncthreads();
#pragma unroll
  for (int e = 0; e < 6; ++e) {
    int idx = e * 512 + t;
    int ky = idx >> 10;
    int i = (idx >> 5) & 31;
    int j = idx & 31;
    const u16* P0 = Zl + (ky * 3 + 0) * 1024 + i * 32;
    const u16* P1 = P0 + 1024;
    const u16* P2 = P0 + 2048;
    float Ej = bf2f(P0[j]) + (j >= 1 ? bf2f(P2[j - 1]) : 0.f);
    float Ej1 = (j < 31 ? bf2f(P0[j + 1]) : 0.f) + bf2f(P2[j]);
    float Ojm = j >= 1 ? bf2f(P1[j - 1]) : 0.f;
    float Oj = bf2f(P1[j]);
    float Ojp = j < 31 ? bf2f(P1[j + 1]) : 0.f;
    float* hp = Hl + ky * 2048 + i * 64 + j;
    hp[0] = Ojm + 3.f * Ej + 3.f * Oj + Ej1;
    hp[32] = Ej + 3.f * Oj + 3.f * Ej1 + Ojp;
  }
  __syncthreads();
  const float dc = dcoef[b * 512 + o] * 0.0625f;
  const float ns = nstr[0];
  const float bo = bias[o];
  const int q = t & 15;           // j-quad: cols 4q..4q+3
  const int i = t >> 4;           // 0..31 -> out rows 2i, 2i+1
  const int cb = 2 * q;           // column base within H halves
#define LD2(ky_, r_) *(const float2*)(Hl + (ky_) * 2048 + (r_) * 64 + cb)
#define LD2H(ky_, r_) *(const float2*)(Hl + (ky_) * 2048 + (r_) * 64 + 32 + cb)
  const float2 z2 = {0.f, 0.f};
  float2 A0c = LD2(0, i), B0c = LD2H(0, i);
  float2 A1c = LD2(1, i), B1c = LD2H(1, i);
  float2 A2c = LD2(2, i), B2c = LD2H(2, i);
  float2 A0n = (i < 31) ? LD2(0, i + 1) : z2;
  float2 B0n = (i < 31) ? LD2H(0, i + 1) : z2;
  float2 A1n = (i < 31) ? LD2(1, i + 1) : z2;
  float2 B1n = (i < 31) ? LD2H(1, i + 1) : z2;
  float2 A1p = (i > 0) ? LD2(1, i - 1) : z2;
  float2 B1p = (i > 0) ? LD2H(1, i - 1) : z2;
  float2 A2p = (i > 0) ? LD2(2, i - 1) : z2;
  float2 B2p = (i > 0) ? LD2H(2, i - 1) : z2;
#undef LD2
#undef LD2H
  const int m = 2 * i;
  const float* nzb = noise + ((size_t)b << 12) + (size_t)m * 64 + 4 * q;
  const float4 nz0 = *(const float4*)(nzb);
  const float4 nz1 = *(const float4*)(nzb + 64);
  float ev[4], od[4];
#define COLS(c_, f_)                                                     \
  ev[c_] = f_(A1p, B1p) + 3.f * (f_(A0c, B0c) + f_(A2p, B2p)) +          \
           3.f * f_(A1c, B1c) + (f_(A0n, B0n) + f_(A2c, B2c));           \
  od[c_] = (f_(A0c, B0c) + f_(A2p, B2p)) + 3.f * f_(A1c, B1c) +          \
           3.f * (f_(A0n, B0n) + f_(A2c, B2c)) + f_(A1n, B1n)
#define FAX(a_, b_) (a_.x)
#define FBX(a_, b_) (b_.x)
#define FAY(a_, b_) (a_.y)
#define FBY(a_, b_) (b_.y)
  COLS(0, FAX);
  COLS(1, FBX);
  COLS(2, FAY);
  COLS(3, FBY);
#undef COLS
#undef FAX
#undef FBX
#undef FAY
#undef FBY
  float4 r0, r1;
  {
    const float nzs0[4] = {nz0.x, nz0.y, nz0.z, nz0.w};
    const float nzs1[4] = {nz1.x, nz1.y, nz1.z, nz1.w};
    float o0[4], o1[4];
#pragma unroll
    for (int c = 0; c < 4; ++c) {
      float v0 = ev[c] * dc + nzs0[c] * ns + bo;
      v0 = (v0 > 0.f ? v0 : 0.2f * v0) * 1.4142135623730951f;
      o0[c] = fminf(fmaxf(v0, -256.f), 256.f);
      float v1 = od[c] * dc + nzs1[c] * ns + bo;
      v1 = (v1 > 0.f ? v1 : 0.2f * v1) * 1.4142135623730951f;
      o1[c] = fminf(fmaxf(v1, -256.f), 256.f);
    }
    r0 = {o0[0], o0[1], o0[2], o0[3]};
    r1 = {o1[0], o1[1], o1[2], o1[3]};
  }
  float* ob = out + (((size_t)(b * 512 + o)) << 12) + (size_t)m * 64 + 4 * q;
  *(float4*)(ob) = r0;
  *(float4*)(ob + 64) = r1;
}

extern "C" void kernel_launch(void* const* d_in, const int* in_sizes, int n_in,
                              void* d_out, int out_size, void* d_ws, size_t ws_size,
                              hipStream_t stream) {
  const float* x = (const float*)d_in[0];
  const float* wl = (const float*)d_in[1];
  const float* aw = (const float*)d_in[2];
  const float* ab = (const float*)d_in[3];
  const float* cw = (const float*)d_in[4];
  const float* noise = (const float*)d_in[5];
  const float* nstr = (const float*)d_in[6];
  const float* bias = (const float*)d_in[7];
  float* out = (float*)d_out;

  float* style = (float*)d_ws;
  float* dcoef = style + 8192;
  u16* W2 = (u16*)(dcoef + 8192);
  u16* xT = W2 + 4608 * 512;
  u16* Z = xT + (size_t)16384 * 512;

  k_style<<<dim3(8, 16), 256, 0, stream>>>(wl, aw, ab, style);
  k_wprep<<<dim3(512), 256, 0, stream>>>(cw, style, dcoef, W2);
  k_xt<<<dim3(16, 8, 16), 256, 0, stream>>>(x, style, xT);
  k_gemm<<<dim3(64, 36), 512, 0, stream>>>(W2, xT, Z);
  k_scatter<<<dim3(512, 16), 512, 0, stream>>>(Z, dcoef, noise, nstr, bias, out);
}

// Round 11
// 323.519 us; speedup vs baseline: 1.0354x; 1.0007x over previous
//
#include <hip/hip_runtime.h>
#include <hip/hip_bf16.h>

// SynthesisConv: style affine -> demod -> conv_transpose(up=2,k=3) -> FIR 4x4
// -> noise + bias + lrelu*sqrt(2) + clamp(+-256).  Inputs f32, output f32.
//
//   style folds into x (B-operand column scale), dcoef folds into epilogue.
//   Z[(o,ky,kx),(b,i,j)] = sum_c w[o,c,ky,kx] * x'[b,c,i,j]   (one shared GEMM)
// R7: k_gemm LDS chunk-swizzle kills the 8-way ds_read_b128 bank conflict.
// R8: 256x256, 4-buffer ring, counted vmcnt, setprio (null).
// R9: XCD swizzle (REGRESSED); k_style coalesced rewrite kept.
// R10: barriers 5->1 per K-tile + LDS-staged coalesced C-write (WIN).
// R11: k_scatter 512 thr -> 24 waves/CU (WIN).
// R12: m201-style 4-phase fine interleave (null; schedule family exhausted).
// R13: k_gemm 128x256, 2 blocks/CU (WIN 102.8->92.9).
// R14: k_scatter phase-3 + k_xt vectorize (WIN 338->321; gemm flat).
// R15: k_gemm 128x128 4-block attempt (REGRESSED; axis closed).
// R16/17: gemm R13 verbatim (confirmed restored) + scatter gload_lds (~flat).
// R18: k_scatter single-phase: eliminate Hl (24KB) entirely; each thread
//      recomputes its 7 needed H-row-segments from Zl directly (49 LDS ops
//      vs 82 incl. Hl roundtrip). LDS 42->18KB -> 4 blocks/CU (32 waves,
//      +33% TLP), barriers 3->1. Expression order preserved -> bit-identical.

typedef unsigned short u16;
typedef unsigned int u32;
typedef u16 u16x2 __attribute__((ext_vector_type(2)));
typedef u16 u16x8 __attribute__((ext_vector_type(8)));
typedef __bf16 bf16x8 __attribute__((ext_vector_type(8)));
typedef float f32x4 __attribute__((ext_vector_type(4)));

#define NB 16

__device__ __forceinline__ float bf2f(u16 v) {
  unsigned int u = ((unsigned int)v) << 16;
  float f;
  __builtin_memcpy(&f, &u, 4);
  return f;
}
__device__ __forceinline__ u16 f2bf(float f) {
  __hip_bfloat16 h = __float2bfloat16(f);  // RNE
  u16 r;
  __builtin_memcpy(&r, &h, 2);
  return r;
}
__device__ __forceinline__ void async16(u16* lds, const u16* g) {
  __builtin_amdgcn_global_load_lds(
      (const __attribute__((address_space(1))) u32*)g,
      (__attribute__((address_space(3))) u32*)lds, 16, 0, 0);
}

// ---- style[b,c] = sum_k wl[b,k]*aw[c,k]/sqrt(512) + ab[c] ---------------------
__global__ __launch_bounds__(256) void k_style(const float* __restrict__ wl,
                                               const float* __restrict__ aw,
                                               const float* __restrict__ ab,
                                               float* __restrict__ style) {
  __shared__ float lw[512];
  const int b = blockIdx.y;
  const int c0 = blockIdx.x << 6;
  const int t = threadIdx.x;
  for (int k = t; k < 512; k += 256) lw[k] = wl[b * 512 + k];
  __syncthreads();
  const int w = t >> 6, l = t & 63;
  const float4 lv0 = *(const float4*)(lw + (l << 2));
  const float4 lv1 = *(const float4*)(lw + 256 + (l << 2));
  for (int r = w; r < 64; r += 4) {
    const int c = c0 + r;
    const float* row = aw + (size_t)c * 512 + (l << 2);
    const float4 a0 = *(const float4*)(row);
    const float4 a1 = *(const float4*)(row + 256);
    float acc = lv0.x * a0.x + lv0.y * a0.y + lv0.z * a0.z + lv0.w * a0.w +
                lv1.x * a1.x + lv1.y * a1.y + lv1.z * a1.z + lv1.w * a1.w;
#pragma unroll
    for (int off = 32; off; off >>= 1) acc += __shfl_down(acc, off, 64);
    if (l == 0) style[b * 512 + c] = acc * 0.04419417382415922f + ab[c];
  }
}

// ---- merged: W2 pack (bf16, [o*9+kp][c]) + dcoef[b,o] ------------------------
__global__ __launch_bounds__(256) void k_wprep(const float* __restrict__ cw,
                                               const float* __restrict__ style,
                                               float* __restrict__ dcoef,
                                               u16* __restrict__ W2) {
  __shared__ u16 lw[4608];
  __shared__ float wsq[512];
  const int o = blockIdx.x, t = threadIdx.x;
  const float* src = cw + (size_t)o * 4608;
  for (int v = t; v < 4608; v += 256) {
    unsigned c = (unsigned)v / 9u;
    unsigned kp = (unsigned)v % 9u;
    lw[kp * 512 + c] = f2bf(src[v]);
  }
  for (int c = t; c < 512; c += 256) {
    const float* p = src + (size_t)c * 9;
    float s = 0.f;
#pragma unroll
    for (int k = 0; k < 9; ++k) {
      float v = p[k];
      s += v * v;
    }
    wsq[c] = s;
  }
  __syncthreads();
  u16* dst = W2 + (size_t)o * 4608;
  for (int v = t; v < 576; v += 256)
    *(u16x8*)(dst + v * 8) = *(const u16x8*)(lw + v * 8);
  const int w = t >> 6, l = t & 63;
  for (int b = w; b < NB; b += 4) {
    float part = 0.f;
#pragma unroll
    for (int c = l; c < 512; c += 64) {
      float st = style[b * 512 + c];
      part += st * st * wsq[c];
    }
#pragma unroll
    for (int off = 32; off; off >>= 1) part += __shfl_down(part, off, 64);
    if (l == 0) dcoef[b * 512 + o] = 1.0f / sqrtf(part + 1e-8f);
  }
}

// ---- xT[b,s,c] = bf16(x[b,c,s] * style[b,c])  (LDS 64x64 transpose) ----------
__global__ __launch_bounds__(256) void k_xt(const float* __restrict__ x,
                                            const float* __restrict__ style,
                                            u16* __restrict__ xT) {
  __shared__ u16 tile[64 * 66];
  const int b = blockIdx.z, c0 = blockIdx.y << 6, s0 = blockIdx.x << 6;
  const int t = threadIdx.x;
#pragma unroll
  for (int i = 0; i < 4; ++i) {
    int e = i * 256 + t;
    int cc = e >> 4, f4 = e & 15;   // 64 rows x 16 float4
    int c = c0 + cc;
    float4 v = *(const float4*)(x + (size_t)(b * 512 + c) * 1024 + s0 + f4 * 4);
    float sv = style[b * 512 + c];
    int base = cc * 66 + f4 * 4;    // even -> 4B aligned for u16x2
    u16x2 p0, p1;
    p0[0] = f2bf(v.x * sv);
    p0[1] = f2bf(v.y * sv);
    p1[0] = f2bf(v.z * sv);
    p1[1] = f2bf(v.w * sv);
    *(u16x2*)(tile + base) = p0;
    *(u16x2*)(tile + base + 2) = p1;
  }
  __syncthreads();
#pragma unroll
  for (int e = 0; e < 2; ++e) {
    int idx = e * 256 + t;          // 512 = 64 rows x 8 col-groups
    int sc = idx >> 3;
    int cg = (idx & 7) << 3;
    u16x8 v;
#pragma unroll
    for (int g = 0; g < 8; ++g) v[g] = tile[(cg + g) * 66 + sc];
    *(u16x8*)(xT + (size_t)(b * 1024 + s0 + sc) * 512 + c0 + cg) = v;
  }
}

// ---- GEMM: Z[4608 x 16384] = W2[4608 x 512] * xT[16384 x 512]^T --------------
// R13: 128x256 tile, BK=32, 8 waves (2M x 4N, wave tile 64x64, acc[4][4]).
// 3-buffer ring, 2-tile-deep prefetch, counted vmcnt(3), 1 barrier/tile,
// setprio. 2 blocks/CU. R7 chunk swizzle. C via LDS [128][264] union.
__global__ __launch_bounds__(512, 4) void k_gemm(const u16* __restrict__ W2,
                                                 const u16* __restrict__ xT,
                                                 u16* __restrict__ Z) {
  __shared__ union SM {
    struct { u16 A[3][4096]; u16 B[3][8192]; } g;  // 72 KiB ring
    u16 C[128 * 264];                              // 66 KiB epilogue tile
  } sm;
  const int t = threadIdx.x;
  const int m0 = blockIdx.y << 7;   // 36 m-blocks
  const int n0 = blockIdx.x << 8;   // 64 n-blocks
  const int l = t & 63;
  const int w = t >> 6;        // wave 0..7
  const int wm = w >> 2;       // 0..1  (M half: 64 rows)
  const int wn = w & 3;        // 0..3  (N quarter: 64 cols)
  const int lrow = l & 15;
  const int lk = l >> 4;       // k-chunk 0..3

  const int sr = t >> 2;
  const int sch = ((t & 3) + (sr >> 1)) & 3;
  const u16* gA = W2 + (size_t)(m0 + sr) * 512 + (sch << 3);
  const u16* gB = xT + (size_t)(n0 + sr) * 512 + (sch << 3);
  const int stg = t << 3;      // u16 offset in 8 KB slab

  const int sk8 = ((lk - (lrow >> 1)) & 3) << 3;
  const int arow = (wm << 6) + lrow;
  const int brow = (wn << 6) + lrow;

  f32x4 acc[4][4] = {};

#define STG(buf_, kt_)                                              \
  async16(&sm.g.A[buf_][stg], gA + (kt_) * 32);                     \
  async16(&sm.g.B[buf_][stg], gB + (kt_) * 32);                     \
  async16(&sm.g.B[buf_][4096 + stg], gB + (kt_) * 32 + 128 * 512)

  STG(0, 0);
  STG(1, 1);
  asm volatile("s_waitcnt vmcnt(3)" ::: "memory");
  asm volatile("s_barrier" ::: "memory");

  int buf = 0, nxt = 2;
  for (int kt = 0; kt < 16; ++kt) {
    const u16* Ab = sm.g.A[buf];
    const u16* Bb = sm.g.B[buf];
    bf16x8 av[4], bv[4];
#pragma unroll
    for (int i = 0; i < 4; ++i)
      av[i] = *(const bf16x8*)(Ab + (arow + i * 16) * 32 + sk8);
#pragma unroll
    for (int j = 0; j < 4; ++j)
      bv[j] = *(const bf16x8*)(Bb + (brow + j * 16) * 32 + sk8);
    if (kt < 14) { STG(nxt, kt + 2); }
    asm volatile("s_waitcnt lgkmcnt(0)" ::: "memory");
    __builtin_amdgcn_sched_barrier(0);
    __builtin_amdgcn_s_setprio(1);
#pragma unroll
    for (int i = 0; i < 4; ++i)
#pragma unroll
      for (int j = 0; j < 4; ++j)
        acc[i][j] = __builtin_amdgcn_mfma_f32_16x16x32_bf16(av[i], bv[j], acc[i][j], 0, 0, 0);
    __builtin_amdgcn_s_setprio(0);
    if (kt <= 13) {
      asm volatile("s_waitcnt vmcnt(3)" ::: "memory");
    } else if (kt == 14) {
      asm volatile("s_waitcnt vmcnt(0)" ::: "memory");
    }
    asm volatile("s_barrier" ::: "memory");
    buf = (buf == 2) ? 0 : buf + 1;
    nxt = (nxt == 2) ? 0 : nxt + 1;
  }
#undef STG

  __syncthreads();  // ring dead; reuse LDS as C tile
  const int crow0 = (wm << 6) + (lk << 2);
  const int ccol0 = (wn << 6) + lrow;
#pragma unroll
  for (int i = 0; i < 4; ++i)
#pragma unroll
    for (int j = 0; j < 4; ++j)
#pragma unroll
      for (int r = 0; r < 4; ++r)
        sm.C[(crow0 + i * 16 + r) * 264 + ccol0 + j * 16] = f2bf(acc[i][j][r]);
  __syncthreads();
  u16* zb = Z + (size_t)m0 * 16384 + n0;
#pragma unroll
  for (int k = 0; k < 8; ++k) {
    int c = (k << 9) | t;
    int row = c >> 5;
    int c8 = (c & 31) << 3;
    *(u16x8*)(zb + (size_t)row * 16384 + c8) = *(const u16x8*)(sm.C + row * 264 + c8);
  }
}

// ---- scatter helper: horizontal-FIR row segment -------------------------------
// Returns (he(j), ho(j), he(j+1), ho(j+1)) of plane-group ky at row r, j=2q.
// Expressions match the old phase-1 forms exactly (bit-identical).
__device__ __forceinline__ f32x4 hrow4(const u16* __restrict__ Zl, int ky,
                                       int r, int j) {
  f32x4 h = {0.f, 0.f, 0.f, 0.f};
  if ((unsigned)r > 31u) return h;
  const u16* P0 = Zl + ky * 3 * 1024 + r * 32;
  const u16* P1 = P0 + 1024;
  const u16* P2 = P0 + 2048;
  u16x2 v0 = *(const u16x2*)(P0 + j);
  u16x2 v1 = *(const u16x2*)(P1 + j);
  u16x2 v2 = *(const u16x2*)(P2 + j);
  float p0a = bf2f(v0[0]), p0b = bf2f(v0[1]);
  float p1a = bf2f(v1[0]), p1b = bf2f(v1[1]);
  float p2a = bf2f(v2[0]), p2b = bf2f(v2[1]);
  float p0c = (j < 30) ? bf2f(P0[j + 2]) : 0.f;
  float p1c = (j < 30) ? bf2f(P1[j + 2]) : 0.f;
  float p1m = (j >= 1) ? bf2f(P1[j - 1]) : 0.f;
  float p2m = (j >= 1) ? bf2f(P2[j - 1]) : 0.f;
  float Ej = p0a + p2m;    // P0[j]   + P2[j-1]
  float Ej1 = p0b + p2a;   // P0[j+1] + P2[j]
  float Ej2 = p0c + p2b;   // P0[j+2] + P2[j+1]
  h[0] = p1m + 3.f * Ej + 3.f * p1a + Ej1;   // he(j)   -> out col 4q+0
  h[1] = Ej + 3.f * p1a + 3.f * Ej1 + p1b;   // ho(j)   -> out col 4q+1
  h[2] = p1a + 3.f * Ej1 + 3.f * p1b + Ej2;  // he(j+1) -> out col 4q+2
  h[3] = Ej1 + 3.f * p1b + 3.f * Ej2 + p1c;  // ho(j+1) -> out col 4q+3
  return h;
}

// ---- scatter: polyphase separable FIR + epilogue (single phase) --------------
// R18: Zl only (18 KB); thread (i = t>>4, q = t&15) computes out rows 2i,2i+1
// cols 4q..4q+3 by recomputing its 7 H-row-segments directly from Zl.
__global__ __launch_bounds__(512, 8) void k_scatter(
    const u16* __restrict__ Z, const float* __restrict__ dcoef,
    const float* __restrict__ noise, const float* __restrict__ nstr,
    const float* __restrict__ bias, float* __restrict__ out) {
  __shared__ u16 Zl[9 * 1024];
  const int o = blockIdx.x;
  const int b = blockIdx.y;
  const int t = threadIdx.x;
  const u16* Zp = Z + (size_t)o * 9 * 16384 + (size_t)b * 1024;
  for (int v = t; v < 1152; v += 512) {
    async16(Zl + (v << 3), Zp + (size_t)(v >> 7) * 16384 + ((v & 127) << 3));
  }
  asm volatile("s_waitcnt vmcnt(0)" ::: "memory");
  __syncthreads();

  const float dc = dcoef[b * 512 + o] * 0.0625f;
  const float ns = nstr[0];
  const float bo = bias[o];
  const int q = t & 15;
  const int i = t >> 4;
  const int j = 2 * q;

  // ev = ((H1p + 3*s1) + 3*H1c) + s2 ; od = ((s1 + 3*H1c) + 3*s2) + H1n
  // with s1 = H0c + H2p, s2 = H0n + H2c  (same grouping/order as before).
  f32x4 s1;
  {
    f32x4 H0c = hrow4(Zl, 0, i, j);
    f32x4 H2p = hrow4(Zl, 2, i - 1, j);
    s1 = H0c + H2p;
  }
  f32x4 ev, od;
  {
    f32x4 H1p = hrow4(Zl, 1, i - 1, j);
    ev = H1p + 3.f * s1;
    od = s1;
  }
  {
    f32x4 H1c = hrow4(Zl, 1, i, j);
    ev = ev + 3.f * H1c;
    od = od + 3.f * H1c;
  }
  {
    f32x4 H0n = hrow4(Zl, 0, i + 1, j);
    f32x4 H2c = hrow4(Zl, 2, i, j);
    f32x4 s2 = H0n + H2c;
    ev = ev + s2;
    od = od + 3.f * s2;
  }
  {
    f32x4 H1n = hrow4(Zl, 1, i + 1, j);
    od = od + H1n;
  }

  const int m = 2 * i;
  const float* nzb = noise + ((size_t)b << 12) + (size_t)m * 64 + 4 * q;
  const float4 nz0 = *(const float4*)(nzb);
  const float4 nz1 = *(const float4*)(nzb + 64);
  const float nzs0[4] = {nz0.x, nz0.y, nz0.z, nz0.w};
  const float nzs1[4] = {nz1.x, nz1.y, nz1.z, nz1.w};
  float o0[4], o1[4];
#pragma unroll
  for (int c = 0; c < 4; ++c) {
    float v0 = ev[c] * dc + nzs0[c] * ns + bo;
    v0 = (v0 > 0.f ? v0 : 0.2f * v0) * 1.4142135623730951f;
    o0[c] = fminf(fmaxf(v0, -256.f), 256.f);
    float v1 = od[c] * dc + nzs1[c] * ns + bo;
    v1 = (v1 > 0.f ? v1 : 0.2f * v1) * 1.4142135623730951f;
    o1[c] = fminf(fmaxf(v1, -256.f), 256.f);
  }
  float4 r0 = {o0[0], o0[1], o0[2], o0[3]};
  float4 r1 = {o1[0], o1[1], o1[2], o1[3]};
  float* ob = out + (((size_t)(b * 512 + o)) << 12) + (size_t)m * 64 + 4 * q;
  *(float4*)(ob) = r0;
  *(float4*)(ob + 64) = r1;
}

extern "C" void kernel_launch(void* const* d_in, const int* in_sizes, int n_in,
                              void* d_out, int out_size, void* d_ws, size_t ws_size,
                              hipStream_t stream) {
  const float* x = (const float*)d_in[0];
  const float* wl = (const float*)d_in[1];
  const float* aw = (const float*)d_in[2];
  const float* ab = (const float*)d_in[3];
  const float* cw = (const float*)d_in[4];
  const float* noise = (const float*)d_in[5];
  const float* nstr = (const float*)d_in[6];
  const float* bias = (const float*)d_in[7];
  float* out = (float*)d_out;

  float* style = (float*)d_ws;
  float* dcoef = style + 8192;
  u16* W2 = (u16*)(dcoef + 8192);
  u16* xT = W2 + 4608 * 512;
  u16* Z = xT + (size_t)16384 * 512;

  k_style<<<dim3(8, 16), 256, 0, stream>>>(wl, aw, ab, style);
  k_wprep<<<dim3(512), 256, 0, stream>>>(cw, style, dcoef, W2);
  k_xt<<<dim3(16, 8, 16), 256, 0, stream>>>(x, style, xT);
  k_gemm<<<dim3(64, 36), 512, 0, stream>>>(W2, xT, Z);
  k_scatter<<<dim3(512, 16), 512, 0, stream>>>(Z, dcoef, noise, nstr, bias, out);
}